// Round 13
// baseline (294.579 us; speedup 1.0000x reference)
//
#include <hip/hip_runtime.h>
#include <hip/hip_fp16.h>
#include <math.h>

#define NN 100000
#define EE 1600000
#define ET (EE + NN)          // edges + self loops = 1,700,000
#define NEG 0.2f
#define MSTR 68               // k_mlp LDS row stride (floats)
#define SMASK 0x1FFFF

// CSR-build geometry (fused path, round-8 proven)
#define NBUCK 98              // ceil(NN/1024) buckets of 1024 dst nodes
#define NBLK 416              // ceil(ET/4096) partition blocks
#define BITEMS 4096           // items per partition block (256 thr x 16)
#define BCAP 20480            // bucket capacity (mean 17408, sigma~128)

typedef float4 f4;

// ---------------- init: stats=0, gcnt=0 ----------------
__global__ void k_init(float* stats, int* gcnt) {
    int i = threadIdx.x;
    if (i < 4) stats[i] = 0.f;
    if (i < NBUCK) gcnt[i] = 0;
}

// ---------------- BN statistics ----------------
__global__ void k_bnstats(const float* __restrict__ h, float* stats) {
    int gid = blockIdx.x * blockDim.x + threadIdx.x;
    int stride = gridDim.x * blockDim.x;
    float s0 = 0.f, s1 = 0.f, q0 = 0.f, q1 = 0.f;
    for (int i = gid; i < NN; i += stride) {
        float2 v = reinterpret_cast<const float2*>(h)[i];
        s0 += v.x; q0 += v.x * v.x;
        s1 += v.y; q1 += v.y * v.y;
    }
#pragma unroll
    for (int off = 32; off >= 1; off >>= 1) {
        s0 += __shfl_xor(s0, off);
        s1 += __shfl_xor(s1, off);
        q0 += __shfl_xor(q0, off);
        q1 += __shfl_xor(q1, off);
    }
    if ((threadIdx.x & 63) == 0) {
        atomicAdd(&stats[0], s0); atomicAdd(&stats[1], s1);
        atomicAdd(&stats[2], q0); atomicAdd(&stats[3], q1);
    }
}

// ---------------- layer-1 rank-2 attention coefficients ----------------
__global__ void k_coef(const float* __restrict__ W1, const float* __restrict__ as1,
                       const float* __restrict__ ad1, float* __restrict__ coef) {
    int t = threadIdx.x;
    if (t >= 8) return;
    int sd = t >> 2, hh = (t >> 1) & 1, i = t & 1;
    const float* a = sd ? ad1 : as1;
    float s = 0.f;
    for (int c = 0; c < 32; ++c) s += W1[(hh * 32 + c) * 2 + i] * a[hh * 32 + c];
    coef[t] = s;
}

// ---------------- pack MLP weights for contiguous row streams ----------------
__global__ void k_wprep(const float* __restrict__ w1, const float* __restrict__ w2,
                        const float* __restrict__ w3, const float* __restrict__ w4,
                        const float* __restrict__ w5,
                        float* __restrict__ Wt, float* __restrict__ Wt5) {
    int idx = blockIdx.x * blockDim.x + threadIdx.x;
    if (idx < 4 * 4096) {
        int L = idx >> 12;
        int r = idx & 4095;
        int q = r >> 10;
        int t = r & 1023;
        int i = t >> 4, j = t & 15;
        const float* W = (L == 0) ? w1 : (L == 1) ? w2 : (L == 2) ? w3 : w4;
        Wt[idx] = W[(q * 16 + j) * 64 + i];
    }
    if (idx < 1024) {
        int i = idx >> 4, c = idx & 15;
        int w = c >> 2, j = c & 3;
        int o = 3 * w + j;
        int ocnt = (w == 3) ? 2 : 3;
        Wt5[idx] = (j < ocnt) ? w5[o * 64 + i] : 0.f;
    }
}

// ---------------- fused CSR partition: LDS hist + atomic run reservation + scatter ----------------
__global__ void __launch_bounds__(256) k_fpart(const int* __restrict__ ei, int* gcnt,
                                               unsigned* __restrict__ pairs) {
    __shared__ int hist[NBUCK];
    __shared__ int cur[NBUCK];
    int tid = threadIdx.x, blk = blockIdx.x;
    if (tid < NBUCK) hist[tid] = 0;
    int ss[16], dd[16];
    int base = blk * BITEMS;
    __syncthreads();
#pragma unroll
    for (int it = 0; it < 16; ++it) {
        int i = base + it * 256 + tid;
        int s = 0, d = -1;
        if (i < ET) {
            if (i < EE) { s = ei[i]; d = ei[EE + i]; }
            else { s = d = i - EE; }
            atomicAdd(&hist[d >> 10], 1);
        }
        ss[it] = s; dd[it] = d;
    }
    __syncthreads();
    if (tid < NBUCK) cur[tid] = tid * BCAP + atomicAdd(&gcnt[tid], hist[tid]);
    __syncthreads();
#pragma unroll
    for (int it = 0; it < 16; ++it) {
        int d = dd[it];
        if (d >= 0) {
            int pos = atomicAdd(&cur[d >> 10], 1);
            pairs[pos] = (unsigned)ss[it] | ((unsigned)(d & 1023) << 17);
        }
    }
}

// ---------------- 98-entry exclusive scan -> real bucket offsets ----------------
__global__ void k_scan98(const int* __restrict__ gcnt, int* __restrict__ rboff) {
    __shared__ int sm[128];
    int tid = threadIdx.x;
    int v = (tid < NBUCK) ? gcnt[tid] : 0;
    sm[tid] = v;
    __syncthreads();
    for (int off = 1; off < 128; off <<= 1) {
        int t = (tid >= off) ? sm[tid - off] : 0;
        __syncthreads();
        sm[tid] += t;
        __syncthreads();
    }
    if (tid < NBUCK) rboff[tid] = sm[tid] - v;
    if (tid == 0) rboff[NBUCK] = ET;
}

// ---------------- per-bucket local CSR (rowptr + srcl) ----------------
__global__ void __launch_bounds__(1024) k_bucket(const unsigned* __restrict__ pairs,
                                                 const int* __restrict__ gcnt,
                                                 const int* __restrict__ rboff,
                                                 int* __restrict__ rowptr,
                                                 int* __restrict__ srcl) {
    __shared__ int sh[1024];
    __shared__ int se[1024];
    int b = blockIdx.x, tid = threadIdx.x;
    int cnt = gcnt[b];
    int ibase = b * BCAP;
    int obase = rboff[b];
    sh[tid] = 0;
    __syncthreads();
    for (int k = tid; k < cnt; k += 1024) atomicAdd(&sh[pairs[ibase + k] >> 17], 1);
    __syncthreads();
    int deg = sh[tid];
    se[tid] = deg;
    __syncthreads();
    for (int off = 1; off < 1024; off <<= 1) {
        int t = (tid >= off) ? se[tid - off] : 0;
        __syncthreads();
        se[tid] += t;
        __syncthreads();
    }
    int excl = se[tid] - deg;
    int node = (b << 10) + tid;
    if (node < NN) rowptr[node] = obase + excl;
    sh[tid] = obase + excl;     // cursor
    __syncthreads();
    for (int k = tid; k < cnt; k += 1024) {
        unsigned p = pairs[ibase + k];
        int pos = atomicAdd(&sh[p >> 17], 1);
        srcl[pos] = (int)(p & SMASK);
    }
    if (b == 0 && tid == 0) rowptr[NN] = ET;
}

// ---------------- layer-1 prep: BN apply + rank-2 attention scalars ----------------
__global__ void k_prep1(const float* __restrict__ h, const float* __restrict__ stats,
                        const float* __restrict__ gamma, const float* __restrict__ beta,
                        const float* __restrict__ coef,
                        f4* __restrict__ nd1, float2* __restrict__ ed1) {
    int n = blockIdx.x * blockDim.x + threadIdx.x;
    if (n >= NN) return;
    const float inv = 1.f / (float)NN;
    float mu0 = stats[0] * inv, mu1 = stats[1] * inv;
    float v0 = stats[2] * inv - mu0 * mu0;
    float v1 = stats[3] * inv - mu1 * mu1;
    float g0 = rsqrtf(v0 + 1e-5f) * gamma[0];
    float g1 = rsqrtf(v1 + 1e-5f) * gamma[1];
    float2 hv = reinterpret_cast<const float2*>(h)[n];
    float x0 = (hv.x - mu0) * g0 + beta[0];
    float x1 = (hv.y - mu1) * g1 + beta[1];
    nd1[n] = make_float4(x0 * coef[0] + x1 * coef[1], x0 * coef[2] + x1 * coef[3], x0, x1);
    ed1[n] = make_float2(x0 * coef[4] + x1 * coef[5], x0 * coef[6] + x1 * coef[7]);
}

// ---------------- layer-1 GAT: thread per dst, 16B gather (L2-resident 1.6MB) ----------------
__global__ void __launch_bounds__(256) k_gat1(
    const f4* __restrict__ nd1, const float2* __restrict__ ed1,
    const int* __restrict__ rowptr, const int* __restrict__ srcl,
    f4* __restrict__ agg1a, float2* __restrict__ agg1s) {
    int n = blockIdx.x * blockDim.x + threadIdx.x;
    if (n >= NN) return;
    int beg = rowptr[n], end = rowptr[n + 1];
    float2 ed = ed1[n];
    float A0 = 0.f, B0 = 0.f, S0 = 0.f, A1 = 0.f, B1 = 0.f, S1 = 0.f;
    for (int k = beg; k < end; ++k) {
        int s = srcl[k];
        f4 p = nd1[s];
        float e0 = p.x + ed.x;
        float e1 = p.y + ed.y;
        e0 = (e0 > 0.f) ? e0 : NEG * e0;
        e1 = (e1 > 0.f) ? e1 : NEG * e1;
        float w0 = __expf(e0);
        float w1 = __expf(e1);
        A0 += w0 * p.z; B0 += w0 * p.w; S0 += w0;
        A1 += w1 * p.z; B1 += w1 * p.w; S1 += w1;
    }
    agg1a[n] = make_float4(A0, B0, A1, B1);
    agg1s[n] = make_float2(S0, S1);
}

// ---------------- layer-1 finalize + linear(64->64) + layer-2 attention scalars ----------------
__global__ void k_xform2f(const f4* __restrict__ agg1a, const float2* __restrict__ agg1s,
                          const float* __restrict__ W1, const float* __restrict__ b1,
                          const float* __restrict__ W, const float* __restrict__ a_s,
                          const float* __restrict__ a_d,
                          __half* __restrict__ xph, float2* __restrict__ es2v,
                          float2* __restrict__ ed2v) {
    int n = blockIdx.x * blockDim.x + threadIdx.x;
    if (n >= NN) return;
    f4 ag = agg1a[n];
    float2 sg = agg1s[n];
    float r0 = 1.f / (sg.x + 1e-16f);
    float r1 = 1.f / (sg.y + 1e-16f);
    float x[64];
#pragma unroll
    for (int f = 0; f < 64; ++f) {
        float A = (f < 32) ? ag.x : ag.z;
        float B = (f < 32) ? ag.y : ag.w;
        float r = (f < 32) ? r0 : r1;
        x[f] = fmaxf((A * W1[2 * f] + B * W1[2 * f + 1]) * r + b1[f], 0.f);
    }
    float es0 = 0.f, es1 = 0.f, ed0 = 0.f, ed1 = 0.f;
    __half2* xo = reinterpret_cast<__half2*>(xph + (size_t)n * 64);
#pragma unroll 1
    for (int fq = 0; fq < 16; ++fq) {
        float vq[4];
#pragma unroll
        for (int j = 0; j < 4; ++j) {
            int f = 4 * fq + j;
            float acc = 0.f;
#pragma unroll
            for (int i = 0; i < 64; ++i) acc += W[f * 64 + i] * x[i];
            vq[j] = acc;
            float ts = acc * a_s[f], td = acc * a_d[f];
            if (fq < 8) { es0 += ts; ed0 += td; } else { es1 += ts; ed1 += td; }
        }
        xo[2 * fq]     = __floats2half2_rn(vq[0], vq[1]);
        xo[2 * fq + 1] = __floats2half2_rn(vq[2], vq[3]);
    }
    es2v[n] = make_float2(es0, es1);
    ed2v[n] = make_float2(ed0, ed1);
}

// ---------------- layer-2 GAT: wave per dst, PAIRED edges, 16 edges in flight ----------------
__global__ void __launch_bounds__(256) k_gat2(
    const __half* __restrict__ xph, const float2* __restrict__ es2v,
    const float2* __restrict__ ed2v,
    const int* __restrict__ rowptr, const int* __restrict__ srcl,
    const float* __restrict__ bias, float* __restrict__ y) {
    int wid = (blockIdx.x * blockDim.x + threadIdx.x) >> 6;
    int lane = threadIdx.x & 63;
    if (wid >= NN) return;
    int l5 = lane & 31;            // channel pair index: channels 2*l5, 2*l5+1
    int hs = lane >> 5;            // 0: even slots, 1: odd slots
    bool headhi = l5 >= 16;        // channels >=32 -> head 1
    int ch = 2 * l5;
    float2 edp = ed2v[wid];
    float edv = headhi ? edp.y : edp.x;
    int beg = rowptr[wid], end = rowptr[wid + 1];
    float sum = 0.f, a0 = 0.f, a1 = 0.f;
    int k = beg;

#define GPAIR(kk)                                                                 \
    {                                                                             \
        int s_ = srcl[(kk) + hs];                                                 \
        float2 ep_ = es2v[s_];                                                    \
        unsigned xr_ = *reinterpret_cast<const unsigned*>(&xph[(size_t)s_ * 64 + ch]); \
        float e_ = (headhi ? ep_.y : ep_.x) + edv;                                \
        e_ = (e_ > 0.f) ? e_ : NEG * e_;                                          \
        float w_ = __expf(e_);                                                    \
        float2 xv_ = __half22float2(*reinterpret_cast<const __half2*>(&xr_));     \
        sum += w_; a0 += w_ * xv_.x; a1 += w_ * xv_.y;                            \
    }

    for (; k + 16 <= end; k += 16) {
        GPAIR(k) GPAIR(k + 2) GPAIR(k + 4) GPAIR(k + 6)
        GPAIR(k + 8) GPAIR(k + 10) GPAIR(k + 12) GPAIR(k + 14)
    }
    for (; k + 8 <= end; k += 8) {
        GPAIR(k) GPAIR(k + 2) GPAIR(k + 4) GPAIR(k + 6)
    }
    for (; k < end; k += 2) {
        int idx = k + hs;
        bool valid = idx < end;
        int s_ = srcl[valid ? idx : k];
        float2 ep_ = es2v[s_];
        unsigned xr_ = *reinterpret_cast<const unsigned*>(&xph[(size_t)s_ * 64 + ch]);
        float e_ = (headhi ? ep_.y : ep_.x) + edv;
        e_ = (e_ > 0.f) ? e_ : NEG * e_;
        float w_ = valid ? __expf(e_) : 0.f;
        float2 xv_ = __half22float2(*reinterpret_cast<const __half2*>(&xr_));
        sum += w_; a0 += w_ * xv_.x; a1 += w_ * xv_.y;
    }
#undef GPAIR

    sum += __shfl_xor(sum, 32);
    a0  += __shfl_xor(a0, 32);
    a1  += __shfl_xor(a1, 32);
    if (lane < 32) {
        float rs = 1.f / (sum + 1e-16f);
        float r0 = fmaxf(a0 * rs + bias[ch], 0.f);
        float r1 = fmaxf(a1 * rs + bias[ch + 1], 0.f);
        *reinterpret_cast<float2*>(&y[(size_t)wid * 64 + ch]) = make_float2(r0, r1);
    }
}

// ---------------- fused 5-layer MLP: LDS-staged weights, 6-deep rolling row window ----------------
// Weight rows read as wave-uniform ds_read_b128 broadcasts (conflict-free); 6 rows in
// flight (96 VGPR) -> 160cy slack vs ~120cy LDS latency -> no per-row stall.
__device__ __forceinline__ void mlayer(const float* __restrict__ wlds, const float* __restrict__ B,
                                       int o0, const float* __restrict__ xrow, float* acc) {
#pragma unroll
    for (int j = 0; j < 16; ++j) acc[j] = B[o0 + j];
    f4 w[6][4];
#pragma unroll
    for (int r = 0; r < 6; ++r)
#pragma unroll
        for (int p = 0; p < 4; ++p)
            w[r][p] = *reinterpret_cast<const f4*>(&wlds[r * 16 + 4 * p]);
    float xc[16];
#pragma unroll
    for (int c = 0; c < 4; ++c) {
#pragma unroll
        for (int q = 0; q < 4; ++q) {
            f4 t = *reinterpret_cast<const f4*>(&xrow[c * 16 + 4 * q]);
            xc[4 * q] = t.x; xc[4 * q + 1] = t.y; xc[4 * q + 2] = t.z; xc[4 * q + 3] = t.w;
        }
#pragma unroll
        for (int i = 0; i < 16; ++i) {
            const int gi = c * 16 + i;
            const int sl = gi % 6;
            float xi = xc[i];
            acc[0]  += w[sl][0].x * xi;
            acc[1]  += w[sl][0].y * xi;
            acc[2]  += w[sl][0].z * xi;
            acc[3]  += w[sl][0].w * xi;
            acc[4]  += w[sl][1].x * xi;
            acc[5]  += w[sl][1].y * xi;
            acc[6]  += w[sl][1].z * xi;
            acc[7]  += w[sl][1].w * xi;
            acc[8]  += w[sl][2].x * xi;
            acc[9]  += w[sl][2].y * xi;
            acc[10] += w[sl][2].z * xi;
            acc[11] += w[sl][2].w * xi;
            acc[12] += w[sl][3].x * xi;
            acc[13] += w[sl][3].y * xi;
            acc[14] += w[sl][3].z * xi;
            acc[15] += w[sl][3].w * xi;
            if (gi + 6 < 64) {
#pragma unroll
                for (int p = 0; p < 4; ++p)
                    w[sl][p] = *reinterpret_cast<const f4*>(&wlds[(gi + 6) * 16 + 4 * p]);
            }
        }
    }
}

__global__ void __launch_bounds__(256, 3) k_mlp(
    const float* __restrict__ hin,
    const float* __restrict__ Wt, const float* __restrict__ Wt5,
    const float* __restrict__ b1, const float* __restrict__ b2,
    const float* __restrict__ b3, const float* __restrict__ b4,
    const float* __restrict__ b5,
    float* __restrict__ out) {
    __shared__ float xs[64 * MSTR];
    __shared__ float ws_[4096];          // current layer weights (16KB)
    int lane = threadIdx.x & 63;
    int w = __builtin_amdgcn_readfirstlane(threadIdx.x >> 6);
    int nodeBase = blockIdx.x * 64;
    int node = nodeBase + lane;
    int o0 = w * 16;
    const float* xrow = &xs[lane * MSTR];

    // cooperative load of activations + stage layer-0 weights
#pragma unroll
    for (int i = 0; i < 4; ++i) {
        int v = threadIdx.x + 256 * i;
        int nl = v >> 4;
        int f = (v & 15) << 2;
        f4 t4 = make_float4(0.f, 0.f, 0.f, 0.f);
        if (nodeBase + nl < NN)
            t4 = reinterpret_cast<const f4*>(hin)[(size_t)(nodeBase + nl) * 16 + (v & 15)];
        *reinterpret_cast<f4*>(&xs[nl * MSTR + f]) = t4;
    }
    {
        const f4* wsrc = reinterpret_cast<const f4*>(Wt);
        f4* wd = reinterpret_cast<f4*>(ws_);
        int t = threadIdx.x;
#pragma unroll
        for (int p = 0; p < 4; ++p) wd[t + 256 * p] = wsrc[t + 256 * p];
    }
    __syncthreads();

    float acc[16];
#define MLP_LAYER(L, Bp)                                                         \
    mlayer(ws_ + w * 1024, Bp, o0, xrow, acc);                                   \
    __syncthreads();                                                             \
    _Pragma("unroll")                                                            \
    for (int j = 0; j < 16; j += 4)                                              \
        *reinterpret_cast<f4*>(&xs[lane * MSTR + o0 + j]) =                      \
            make_float4(fmaxf(acc[j], 0.f), fmaxf(acc[j + 1], 0.f),              \
                        fmaxf(acc[j + 2], 0.f), fmaxf(acc[j + 3], 0.f));         \
    if ((L) < 3) {                                                               \
        const f4* wsrc = reinterpret_cast<const f4*>(Wt + ((L) + 1) * 4096);     \
        f4* wd = reinterpret_cast<f4*>(ws_);                                     \
        int t = threadIdx.x;                                                     \
        _Pragma("unroll")                                                        \
        for (int p = 0; p < 4; ++p) wd[t + 256 * p] = wsrc[t + 256 * p];         \
    }                                                                            \
    __syncthreads();

    MLP_LAYER(0, b1)
    MLP_LAYER(1, b2)
    MLP_LAYER(2, b3)
    MLP_LAYER(3, b4)
#undef MLP_LAYER

    int ocnt = (w == 3) ? 2 : 3;
    int ob = w * 3;
    float a5[3];
#pragma unroll
    for (int j = 0; j < 3; ++j) a5[j] = (j < ocnt) ? b5[ob + j] : 0.f;
#pragma unroll
    for (int c = 0; c < 4; ++c) {
        float xc[16];
#pragma unroll
        for (int q = 0; q < 4; ++q) {
            f4 t = *reinterpret_cast<const f4*>(&xrow[c * 16 + 4 * q]);
            xc[4 * q] = t.x; xc[4 * q + 1] = t.y; xc[4 * q + 2] = t.z; xc[4 * q + 3] = t.w;
        }
#pragma unroll
        for (int i = 0; i < 16; ++i) {
            const float* row = &Wt5[(c * 16 + i) * 16 + 4 * w];
#pragma unroll
            for (int j = 0; j < 3; ++j) a5[j] += row[j] * xc[i];
        }
    }
    if (node < NN) {
        for (int j = 0; j < ocnt; ++j) out[(size_t)node * 11 + ob + j] = a5[j];
    }
}

// ---------------- launch ----------------
extern "C" void kernel_launch(void* const* d_in, const int* in_sizes, int n_in,
                              void* d_out, int out_size, void* d_ws, size_t ws_size,
                              hipStream_t stream) {
    const float* h   = (const float*)d_in[0];
    const int*   ei  = (const int*)d_in[1];
    const float* gam = (const float*)d_in[2];
    const float* bet = (const float*)d_in[3];
    const float* W1  = (const float*)d_in[4];
    const float* as1 = (const float*)d_in[5];
    const float* ad1 = (const float*)d_in[6];
    const float* b1  = (const float*)d_in[7];
    const float* W2  = (const float*)d_in[8];
    const float* as2 = (const float*)d_in[9];
    const float* ad2 = (const float*)d_in[10];
    const float* b2  = (const float*)d_in[11];
    const float* fw1 = (const float*)d_in[12];
    const float* fb1 = (const float*)d_in[13];
    const float* fw2 = (const float*)d_in[14];
    const float* fb2 = (const float*)d_in[15];
    const float* fw3 = (const float*)d_in[16];
    const float* fb3 = (const float*)d_in[17];
    const float* fw4 = (const float*)d_in[18];
    const float* fb4 = (const float*)d_in[19];
    const float* fw5 = (const float*)d_in[20];
    const float* fb5 = (const float*)d_in[21];
    float* out = (float*)d_out;

    char* ws = (char*)d_ws;
    size_t off = 0;
    auto alloc = [&](size_t bytes) -> char* {
        char* p = ws + off;
        off += (bytes + 255) & ~(size_t)255;
        return p;
    };
    float* stats  = (float*)alloc(4 * sizeof(float));
    float* coef   = (float*)alloc(8 * sizeof(float));
    int*   gcnt   = (int*)alloc(NBUCK * sizeof(int));
    int*   rboff  = (int*)alloc((NBUCK + 1) * sizeof(int));
    int*   rowptr = (int*)alloc((size_t)(NN + 1) * sizeof(int));
    int*   srcl   = (int*)alloc((size_t)ET * sizeof(int));
    float2* es2v  = (float2*)alloc((size_t)NN * sizeof(float2));
    float2* ed2v  = (float2*)alloc((size_t)NN * sizeof(float2));
    float* Wt     = (float*)alloc((size_t)4 * 4096 * sizeof(float));
    float* Wt5    = (float*)alloc((size_t)1024 * sizeof(float));
    float* bufA   = (float*)alloc((size_t)NN * 64 * sizeof(float));   // pairs -> xph
    float* bufB   = (float*)alloc((size_t)NN * 64 * sizeof(float));
    // aliases (dead before their hosts are written):
    unsigned* pairs = (unsigned*)bufA;                    // 98*20480 u32 = 8MB; dead after k_bucket
    __half* xph   = (__half*)bufA;
    f4*     agg1a = (f4*)bufB;                            // floats [0 .. 400000)
    float2* agg1s = (float2*)(bufB + 400000);             // [400000 .. 600000)
    f4*     nd1   = (f4*)(bufB + 600000);                 // [600000 .. 1000000)
    float2* ed1   = (float2*)(bufB + 1000000);            // [1000000 .. 1200000)
    (void)ws_size; (void)in_sizes; (void)n_in; (void)out_size;

    k_init<<<1, 128, 0, stream>>>(stats, gcnt);
    k_bnstats<<<256, 256, 0, stream>>>(h, stats);
    k_coef<<<1, 64, 0, stream>>>(W1, as1, ad1, coef);
    k_wprep<<<64, 256, 0, stream>>>(fw1, fw2, fw3, fw4, fw5, Wt, Wt5);

    // fused CSR build (round-8 proven)
    k_fpart<<<NBLK, 256, 0, stream>>>(ei, gcnt, pairs);
    k_scan98<<<1, 128, 0, stream>>>(gcnt, rboff);
    k_bucket<<<NBUCK, 1024, 0, stream>>>(pairs, gcnt, rboff, rowptr, srcl);

    // GAT layer 1 (rank-2 path)
    k_prep1<<<(NN + 255) / 256, 256, 0, stream>>>(h, stats, gam, bet, coef, nd1, ed1);
    k_gat1<<<(NN + 255) / 256, 256, 0, stream>>>(nd1, ed1, rowptr, srcl, agg1a, agg1s);

    // layer-1 finalize + layer-2 transform (writes xph=bufA fp16, es2v, ed2v)
    k_xform2f<<<(NN + 255) / 256, 256, 0, stream>>>(agg1a, agg1s, W1, b1, W2, as2, ad2,
                                                    xph, es2v, ed2v);

    // GAT layer 2: paired-edge fp16 gather, 16 edges in flight per wave
    k_gat2<<<(NN * 64) / 256, 256, 0, stream>>>(xph, es2v, ed2v, rowptr, srcl, b2, bufB);

    // MLP head (LDS-staged weights)
    k_mlp<<<(NN + 63) / 64, 256, 0, stream>>>(bufB, Wt, Wt5, fb1, fb2, fb3, fb4, fb5, out);
}